// Round 12
// baseline (435.113 us; speedup 1.0000x reference)
//
#include <hip/hip_runtime.h>

// Problem constants (fixed by reference)
constexpr int NN   = 20000;          // nodes
constexpr int NE   = 320000;         // edges (before self-loops)
constexpr int NTOT = NE + NN;        // edges incl self-loops
constexpr int FIN  = 128;
constexpr int HID  = 256;
constexpr int NG   = 128;            // graphs
constexpr int NCLS = 10;

typedef __bf16 bf16x8 __attribute__((ext_vector_type(8)));
typedef float  f32x4  __attribute__((ext_vector_type(4)));

__device__ __forceinline__ unsigned short f2b(float f) {
  unsigned u = __float_as_uint(f);
  unsigned r = (u + 0x7fffu + ((u >> 16) & 1u)) >> 16;
  return (unsigned short)r;
}
__device__ __forceinline__ float b2f(unsigned short h) {
  return __uint_as_float((unsigned)h << 16);
}

// ---- per-column mean/var partials (grid MUST be 256 blocks; blockDim == C) ----
// Also casts x -> bf16 (covers every element exactly once).
__global__ void colstats_f32_kernel(const float* __restrict__ X, int M,
                                    float* __restrict__ ps, float* __restrict__ pss,
                                    unsigned short* __restrict__ xb) {
  int C = blockDim.x, c = threadIdx.x;
  float s = 0.f, ss = 0.f;
  for (int r = blockIdx.x; r < M; r += 256) {
    float v = X[(size_t)r * C + c];
    s += v; ss += v * v;
    xb[(size_t)r * C + c] = f2b(v);
  }
  ps[blockIdx.x * 256 + c] = s;
  pss[blockIdx.x * 256 + c] = ss;
}

__global__ void colstats_bf16_kernel(const unsigned short* __restrict__ X, int M,
                                     float* __restrict__ ps, float* __restrict__ pss) {
  int C = blockDim.x, c = threadIdx.x;
  float s = 0.f, ss = 0.f;
  for (int r = blockIdx.x; r < M; r += 256) {
    float v = b2f(X[(size_t)r * C + c]);
    s += v; ss += v * v;
  }
  ps[blockIdx.x * 256 + c] = s;
  pss[blockIdx.x * 256 + c] = ss;
}

// ---- fused stats-finalize + weight fold ----
// Thread t reduces the 256 column-partials for k-channel t itself (coalesced,
// L2-hot), computes scale/shift in registers, then folds:
// Wt[n][k] = bf16(sc[k]*W[k][n]); bias2[n] = bias_in[n] + sum_k sh[k]*W[k][n]
__global__ __launch_bounds__(256) void wfold_kernel(const float* __restrict__ W,
    const float* __restrict__ ps, const float* __restrict__ pss,
    const float* __restrict__ g, const float* __restrict__ b,
    const float* __restrict__ bias_in, float invM,
    unsigned short* __restrict__ Wt, float* __restrict__ bias2, int K) {
  int n = blockIdx.x;   // 256 output cols
  int t = threadIdx.x;  // k index
  float part = 0.f;
  if (t < K) {
    float s = 0.f, sq = 0.f;
    for (int j = 0; j < 256; ++j) {
      s  += ps[j * 256 + t];
      sq += pss[j * 256 + t];
    }
    float m = s * invM;
    float var = sq * invM - m * m;
    float sc = g[t] * rsqrtf(var + 1e-5f);
    float sh = b[t] - m * sc;
    float wv = W[(size_t)t * 256 + n];
    Wt[(size_t)n * K + t] = f2b(sc * wv);
    part = sh * wv;
  }
  __shared__ float red[256];
  red[t] = part;
  __syncthreads();
  if (t < 128) red[t] += red[t + 128];
  __syncthreads();
  if (t < 64) {
    float s = red[t] + red[t + 64];
#pragma unroll
    for (int off = 32; off; off >>= 1) s += __shfl_xor(s, off);
    if (t == 0) bias2[n] = (bias_in ? bias_in[n] : 0.f) + s;
  }
}

// ---- pure-bf16 MFMA GEMM + fused attention logits (direct store, no atomics) ----
// C = [relu]( A @ Wt^T + bias2 ); tile 128x128x32, 4 waves (2x2), N fixed 256.
// Block cols [bn,bn+128) = heads (bn>>6)+0 and +1; wave wn owns head (bn>>6)+wn,
// so als[row,head]/ald[row,head] are computed completely within one wave.
__global__ __launch_bounds__(256) void gemm_bf16_kernel(
    const unsigned short* __restrict__ Ab, const unsigned short* __restrict__ Wt,
    const float* __restrict__ bias2, unsigned short* __restrict__ Cb,
    int M, int K, int do_relu,
    float* __restrict__ als, float* __restrict__ ald,
    const float* __restrict__ asrc, const float* __restrict__ adst) {
  __shared__ unsigned short Am[128][40];  // rows padded to 80B (16B aligned)
  __shared__ unsigned short Bn[128][40];
  int tid = threadIdx.x;
  int lane = tid & 63, wid = tid >> 6;
  int wm = wid >> 1, wn = wid & 1;
  int bm = blockIdx.x * 128, bn = blockIdx.y * 128;
  int lrow = lane & 15, lkh = (lane >> 4) * 8;
  int sr = tid >> 2;   // 0..63
  int ssg = tid & 3;   // 16B segment in k (8 bf16)

  f32x4 acc[4][4] = {};

  for (int k0 = 0; k0 < K; k0 += 32) {
    {
      int ra = min(bm + sr, M - 1);
      uint4 v0 = *reinterpret_cast<const uint4*>(Ab + (size_t)ra * K + k0 + ssg * 8);
      *reinterpret_cast<uint4*>(&Am[sr][ssg * 8]) = v0;
      int rb = min(bm + sr + 64, M - 1);
      uint4 v1 = *reinterpret_cast<const uint4*>(Ab + (size_t)rb * K + k0 + ssg * 8);
      *reinterpret_cast<uint4*>(&Am[sr + 64][ssg * 8]) = v1;
      uint4 w0 = *reinterpret_cast<const uint4*>(Wt + (size_t)(bn + sr) * K + k0 + ssg * 8);
      *reinterpret_cast<uint4*>(&Bn[sr][ssg * 8]) = w0;
      uint4 w1 = *reinterpret_cast<const uint4*>(Wt + (size_t)(bn + sr + 64) * K + k0 + ssg * 8);
      *reinterpret_cast<uint4*>(&Bn[sr + 64][ssg * 8]) = w1;
    }
    __syncthreads();
    bf16x8 af[4], bfr[4];
#pragma unroll
    for (int i = 0; i < 4; ++i)
      af[i] = *reinterpret_cast<const bf16x8*>(&Am[wm * 64 + i * 16 + lrow][lkh]);
#pragma unroll
    for (int j = 0; j < 4; ++j)
      bfr[j] = *reinterpret_cast<const bf16x8*>(&Bn[wn * 64 + j * 16 + lrow][lkh]);
#pragma unroll
    for (int i = 0; i < 4; ++i)
#pragma unroll
      for (int j = 0; j < 4; ++j)
        acc[i][j] = __builtin_amdgcn_mfma_f32_16x16x32_bf16(af[i], bfr[j], acc[i][j], 0, 0, 0);
    __syncthreads();
  }

  int r4 = (lane >> 4) * 4;
  bool att = (als != nullptr);
  int head = (bn >> 6) + wn;
  float bv[4], asv[4], adv[4];
#pragma unroll
  for (int j = 0; j < 4; ++j) {
    int colv = bn + wn * 64 + j * 16 + lrow;
    bv[j] = bias2[colv];
    if (att) { asv[j] = asrc[colv]; adv[j] = adst[colv]; }
  }
#pragma unroll
  for (int i = 0; i < 4; ++i) {
#pragma unroll
    for (int r = 0; r < 4; ++r) {
      int row = bm + wm * 64 + i * 16 + r4 + r;
      float ps = 0.f, pd = 0.f;
#pragma unroll
      for (int j = 0; j < 4; ++j) {
        int colv = bn + wn * 64 + j * 16 + lrow;
        float v = acc[i][j][r] + bv[j];
        if (do_relu) v = fmaxf(v, 0.f);
        if (row < M) Cb[(size_t)row * HID + colv] = f2b(v);
        if (att) { ps += v * asv[j]; pd += v * adv[j]; }
      }
      if (att) {
#pragma unroll
        for (int off = 1; off < 16; off <<= 1) {
          ps += __shfl_xor(ps, off);
          pd += __shfl_xor(pd, off);
        }
        if (lrow == 0 && row < M) {
          als[row * 4 + head] = ps;
          ald[row * 4 + head] = pd;
        }
      }
    }
  }
}

// ---- CSR build (dst identical across layers; build once) ----
__device__ __forceinline__ void edge_sd(const int* __restrict__ ei, int e, int& s, int& d) {
  if (e < NE) { s = ei[e]; d = ei[NE + e]; }
  else        { s = e - NE; d = s; }
}

__global__ void hist_kernel(const int* __restrict__ ei, int* __restrict__ deg) {
  int e = blockIdx.x * blockDim.x + threadIdx.x;
  if (e >= NTOT) return;
  int s, d; edge_sd(ei, e, s, d);
  atomicAdd(&deg[d], 1);
}

__global__ __launch_bounds__(1024) void scan_kernel(const int* __restrict__ deg,
                                                    int* __restrict__ rp,
                                                    int* __restrict__ cursor) {
  __shared__ int part[1024];
  int t = threadIdx.x;
  const int C = (NN + 1023) / 1024;
  int base = t * C;
  int s = 0;
  for (int i = 0; i < C; ++i) {
    int idx = base + i;
    if (idx < NN) s += deg[idx];
  }
  part[t] = s;
  __syncthreads();
  for (int off = 1; off < 1024; off <<= 1) {
    int u = (t >= off) ? part[t - off] : 0;
    __syncthreads();
    part[t] += u;
    __syncthreads();
  }
  int run = part[t] - s;
  for (int i = 0; i < C; ++i) {
    int idx = base + i;
    if (idx < NN) {
      rp[idx] = run;
      cursor[idx] = run;
      run += deg[idx];
    }
  }
  if (t == 1023) rp[NN] = part[1023];
}

__global__ void scatter_kernel(const int* __restrict__ ei, int* __restrict__ cursor,
                               int* __restrict__ col) {
  int e = blockIdx.x * blockDim.x + threadIdx.x;
  if (e >= NTOT) return;
  int s, d; edge_sd(ei, e, s, d);
  int pos = atomicAdd(&cursor[d], 1);
  col[pos] = s;
}

// ---- fused GAT aggregation: ONE WAVE PER NODE, single-exp, software-pipelined ----
// Per 16-edge round the dependent chain is col -> als -> exp -> 16 xp gathers.
// Prefetch next round's col AND its als value before the gather loop so both
// latencies hide under the 16 independent xp loads.
__global__ __launch_bounds__(256) void gat_agg_kernel(
    const int* __restrict__ rp, const int* __restrict__ col,
    const float* __restrict__ als, const float* __restrict__ ald,
    const unsigned short* __restrict__ xp, const float* __restrict__ bias,
    unsigned short* __restrict__ out) {
  int wv = threadIdx.x >> 6, lane = threadIdx.x & 63;
  int n = blockIdx.x * 4 + wv;
  if (n >= NN) return;
  int beg = rp[n], deg = rp[n + 1] - beg;   // deg >= 1 (self-loop)
  int hh = lane & 3;       // head this lane computes logits for
  int jof = lane >> 2;     // edge offset within a 16-edge round
  float aldh = ald[n * 4 + hh];
  // phase A: per-head max, col-prefetched
  float m = -1e30f;
  {
    int s = (jof < deg) ? col[beg + jof] : 0;
    for (int r0 = 0; r0 < deg; r0 += 16) {
      int jn = r0 + 16 + jof;
      int snext = (jn < deg) ? col[beg + jn] : 0;
      if (r0 + jof < deg) {
        float l = als[s * 4 + hh] + aldh;
        l = l > 0.f ? l : 0.2f * l;
        m = fmaxf(m, l);
      }
      s = snext;
    }
  }
#pragma unroll
  for (int off = 4; off < 64; off <<= 1) m = fmaxf(m, __shfl_xor(m, off));
  // phase B: exp + unnormalized gather + ssum, col+als prefetched
  int c0 = lane * 4;       // this lane's 4 output channels
  int hme = lane >> 4;     // head of those channels
  float ss = 0.f;
  float a0 = 0.f, a1 = 0.f, a2 = 0.f, a3 = 0.f;
  {
    int s = (jof < deg) ? col[beg + jof] : 0;
    float lv = (jof < deg) ? als[s * 4 + hh] : 0.f;
    for (int r0 = 0; r0 < deg; r0 += 16) {
      int cnt = min(16, deg - r0);
      float cf = 0.f;
      if (jof < cnt) {
        float l = lv + aldh;
        l = l > 0.f ? l : 0.2f * l;
        cf = __expf(l - m);
        ss += cf;
      }
      // prefetch next round (hides under the gather loop below)
      int jn = r0 + 16 + jof;
      int snext = 0; float lnext = 0.f;
      if (jn < deg) { snext = col[beg + jn]; lnext = als[snext * 4 + hh]; }
      if (cnt == 16) {
#pragma unroll
        for (int jj = 0; jj < 16; ++jj) {
          int sj = __shfl(s, jj << 2);
          float c = __shfl(cf, (jj << 2) | hme);
          uint2 w = *reinterpret_cast<const uint2*>(xp + (size_t)sj * HID + c0);
          a0 += c * b2f((unsigned short)(w.x & 0xffff));
          a1 += c * b2f((unsigned short)(w.x >> 16));
          a2 += c * b2f((unsigned short)(w.y & 0xffff));
          a3 += c * b2f((unsigned short)(w.y >> 16));
        }
      } else {
        for (int jj = 0; jj < cnt; ++jj) {
          int sj = __shfl(s, jj << 2);
          float c = __shfl(cf, (jj << 2) | hme);
          uint2 w = *reinterpret_cast<const uint2*>(xp + (size_t)sj * HID + c0);
          a0 += c * b2f((unsigned short)(w.x & 0xffff));
          a1 += c * b2f((unsigned short)(w.x >> 16));
          a2 += c * b2f((unsigned short)(w.y & 0xffff));
          a3 += c * b2f((unsigned short)(w.y >> 16));
        }
      }
      s = snext; lv = lnext;
    }
  }
#pragma unroll
  for (int off = 4; off < 64; off <<= 1) ss += __shfl_xor(ss, off);
  float inv = 1.0f / __shfl(ss, hme);   // lane hme holds the total for head hme
  float4 bvv = *reinterpret_cast<const float4*>(bias + c0);
  ushort4 o;
  o.x = f2b(fmaxf(a0 * inv + bvv.x, 0.f));
  o.y = f2b(fmaxf(a1 * inv + bvv.y, 0.f));
  o.z = f2b(fmaxf(a2 * inv + bvv.z, 0.f));
  o.w = f2b(fmaxf(a3 * inv + bvv.w, 0.f));
  *reinterpret_cast<ushort4*>(out + (size_t)n * HID + c0) = o;
}

// ---- pool: 256 blocks over contiguous node ranges, boundary atomics ----
__global__ void pool_kernel(const unsigned short* __restrict__ h, const int* __restrict__ batch,
                            float* __restrict__ g) {
  const int ROWS = (NN + 255) / 256;
  int r0 = blockIdx.x * ROWS;
  int r1 = min(r0 + ROWS, NN);
  if (r0 >= r1) return;
  int c = threadIdx.x;
  int cur = batch[r0];
  float acc = 0.f;
  for (int r = r0; r < r1; ++r) {
    int b = batch[r];
    if (b != cur) {
      atomicAdd(&g[(size_t)cur * HID + c], acc);
      acc = 0.f;
      cur = b;
    }
    acc += b2f(h[(size_t)r * HID + c]);
  }
  atomicAdd(&g[(size_t)cur * HID + c], acc);
}

// ---- tail: BN (redundant per-block stats, L2-hot) fused into consumers ----
__global__ void fc_bn_kernel(const float* __restrict__ gin, const float* __restrict__ gamma,
                             const float* __restrict__ beta, const float* __restrict__ W,
                             const float* __restrict__ b, float* __restrict__ gout) {
  __shared__ float row[HID];
  int g = blockIdx.x, t = threadIdx.x;  // 256
  float s = 0.f, ss = 0.f;
  for (int r = 0; r < NG; ++r) {
    float v = gin[r * HID + t];
    s += v; ss += v * v;
  }
  float mn = s / NG, var = ss / NG - mn * mn;
  float sc = gamma[t] * rsqrtf(var + 1e-5f);
  float sh = beta[t] - mn * sc;
  row[t] = gin[g * HID + t] * sc + sh;
  __syncthreads();
  float acc = b[t];
  for (int k = 0; k < HID; ++k) acc += row[k] * W[k * HID + t];
  gout[g * HID + t] = fmaxf(acc, 0.f);
}

__global__ void cls_bn_kernel(const float* __restrict__ gin, const float* __restrict__ gamma,
                              const float* __restrict__ beta, const float* __restrict__ W,
                              const float* __restrict__ b, float* __restrict__ out) {
  __shared__ float row[HID];
  __shared__ float logits[NCLS];
  int g = blockIdx.x, t = threadIdx.x;
  float s = 0.f, ss = 0.f;
  for (int r = 0; r < NG; ++r) {
    float v = gin[r * HID + t];
    s += v; ss += v * v;
  }
  float mn = s / NG, var = ss / NG - mn * mn;
  float sc = gamma[t] * rsqrtf(var + 1e-5f);
  float sh = beta[t] - mn * sc;
  row[t] = gin[g * HID + t] * sc + sh;
  __syncthreads();
  if (t < NCLS) {
    float a = b[t];
    for (int k = 0; k < HID; ++k) a += row[k] * W[k * NCLS + t];
    logits[t] = a;
  }
  __syncthreads();
  if (t == 0) {
    float mxv = -1e30f;
    for (int i = 0; i < NCLS; ++i) mxv = fmaxf(mxv, logits[i]);
    float se = 0.f;
    for (int i = 0; i < NCLS; ++i) se += expf(logits[i] - mxv);
    float lse = mxv + logf(se);
    for (int i = 0; i < NCLS; ++i) out[g * NCLS + i] = logits[i] - lse;
  }
}

extern "C" void kernel_launch(void* const* d_in, const int* in_sizes, int n_in,
                              void* d_out, int out_size, void* d_ws, size_t ws_size,
                              hipStream_t stream) {
  const float* x        = (const float*)d_in[0];
  const int*   ei       = (const int*)d_in[1];
  const int*   batch    = (const int*)d_in[2];
  const float* bn_feat_g = (const float*)d_in[3];
  const float* bn_feat_b = (const float*)d_in[4];
  const float* W_feat   = (const float*)d_in[5];
  const float* b_feat   = (const float*)d_in[6];
  const float* bns_g    = (const float*)d_in[7];
  const float* bns_b    = (const float*)d_in[8];
  const float* Wg       = (const float*)d_in[9];
  const float* att_src  = (const float*)d_in[10];
  const float* att_dst  = (const float*)d_in[11];
  const float* gat_b    = (const float*)d_in[12];
  const float* bn_fc_g  = (const float*)d_in[13];
  const float* bn_fc_b  = (const float*)d_in[14];
  const float* W_fc     = (const float*)d_in[15];
  const float* b_fc     = (const float*)d_in[16];
  const float* bn_h_g   = (const float*)d_in[17];
  const float* bn_h_b   = (const float*)d_in[18];
  const float* W_cls    = (const float*)d_in[19];
  const float* b_cls    = (const float*)d_in[20];

  char* ws = (char*)d_ws;
  size_t off = 0;
  auto alloc = [&](size_t bytes) -> void* {
    void* p = ws + off;
    off += (bytes + 255) & ~(size_t)255;
    return p;
  };
  float* psum   = (float*)alloc(256 * 256 * 4);
  float* psumsq = (float*)alloc(256 * 256 * 4);
  float* bias2  = (float*)alloc(HID * 4);
  float* als    = (float*)alloc((size_t)NN * 4 * 4);
  float* ald    = (float*)alloc((size_t)NN * 4 * 4);
  int*   deg    = (int*)alloc((size_t)NN * 4);
  int*   cursor = (int*)alloc((size_t)NN * 4);
  int*   rp     = (int*)alloc((size_t)(NN + 1) * 4);
  int*   col    = (int*)alloc((size_t)NTOT * 4);
  unsigned short* xb  = (unsigned short*)alloc((size_t)NN * FIN * 2);   // x bf16
  unsigned short* Wft = (unsigned short*)alloc((size_t)HID * FIN * 2);  // folded stage0 W
  unsigned short* Wgt = (unsigned short*)alloc((size_t)HID * HID * 2);  // folded layer W (reused)
  unsigned short* bufA = (unsigned short*)alloc((size_t)NN * HID * 2);  // h (bf16)
  unsigned short* xp   = (unsigned short*)alloc((size_t)NN * HID * 2);  // xp (bf16)
  float* g0     = (float*)alloc((size_t)NG * HID * 4);
  float* g1     = (float*)alloc((size_t)NG * HID * 4);
  (void)ws_size; (void)n_in; (void)in_sizes; (void)out_size;

  const int ETHREADS = 256;
  const int EGRID = (NTOT + ETHREADS - 1) / ETHREADS;

  // ---- CSR build (independent of activations)
  hipMemsetAsync(deg, 0, (size_t)NN * 4, stream);
  hist_kernel<<<EGRID, ETHREADS, 0, stream>>>(ei, deg);
  scan_kernel<<<1, 1024, 0, stream>>>(deg, rp, cursor);
  scatter_kernel<<<EGRID, ETHREADS, 0, stream>>>(ei, cursor, col);

  // ---- stage 0: h = bf16(relu( xb @ fold(W_feat) + bias2 ))  (x cast fused in colstats)
  colstats_f32_kernel<<<256, FIN, 0, stream>>>(x, NN, psum, psumsq, xb);
  wfold_kernel<<<HID, 256, 0, stream>>>(W_feat, psum, psumsq, bn_feat_g, bn_feat_b,
                                        b_feat, 1.0f / NN, Wft, bias2, FIN);
  gemm_bf16_kernel<<<dim3((NN + 127) / 128, 2), 256, 0, stream>>>(
      xb, Wft, bias2, bufA, NN, FIN, 1, nullptr, nullptr, nullptr, nullptr);

  // ---- 3 GAT layers
  for (int i = 0; i < 3; ++i) {
    colstats_bf16_kernel<<<256, HID, 0, stream>>>(bufA, NN, psum, psumsq);
    wfold_kernel<<<HID, 256, 0, stream>>>(Wg + (size_t)i * HID * HID, psum, psumsq,
                                          bns_g + i * HID, bns_b + i * HID,
                                          nullptr, 1.0f / NN, Wgt, bias2, HID);
    // xp = bf16(BN(h)@Wg[i]) with fused, direct-store attention logits
    gemm_bf16_kernel<<<dim3((NN + 127) / 128, 2), 256, 0, stream>>>(
        bufA, Wgt, bias2, xp, NN, HID, 0, als, ald,
        att_src + i * HID, att_dst + i * HID);
    gat_agg_kernel<<<(NN + 3) / 4, 256, 0, stream>>>(rp, col, als, ald, xp,
                                                     gat_b + i * HID, bufA);
  }

  // ---- pool + fused tail
  hipMemsetAsync(g0, 0, (size_t)NG * HID * 4, stream);
  pool_kernel<<<256, HID, 0, stream>>>(bufA, batch, g0);
  fc_bn_kernel<<<NG, HID, 0, stream>>>(g0, bn_fc_g, bn_fc_b, W_fc, b_fc, g1);
  cls_bn_kernel<<<NG, HID, 0, stream>>>(g1, bn_h_g, bn_h_b, W_cls, b_cls, (float*)d_out);
}

// Round 13
// 343.736 us; speedup vs baseline: 1.2658x; 1.2658x over previous
//
#include <hip/hip_runtime.h>

// Problem constants (fixed by reference)
constexpr int NN   = 20000;          // nodes
constexpr int NE   = 320000;         // edges (before self-loops)
constexpr int NTOT = NE + NN;        // edges incl self-loops
constexpr int FIN  = 128;
constexpr int HID  = 256;
constexpr int NG   = 128;            // graphs
constexpr int NCLS = 10;

typedef __bf16 bf16x8 __attribute__((ext_vector_type(8)));
typedef float  f32x4  __attribute__((ext_vector_type(4)));

__device__ __forceinline__ unsigned short f2b(float f) {
  unsigned u = __float_as_uint(f);
  unsigned r = (u + 0x7fffu + ((u >> 16) & 1u)) >> 16;
  return (unsigned short)r;
}
__device__ __forceinline__ float b2f(unsigned short h) {
  return __uint_as_float((unsigned)h << 16);
}

// ---- per-column mean/var partials, VECTORIZED (grid MUST be 256 blocks, block 256) ----
// Thread t: channel group g=t&31 (4 f32 ch), row strider rs=t>>5 (0..7).
// Rows r = blockIdx + 256*rs + 2048*k cover every row exactly once.
// Also casts x -> bf16. LDS reduces the 8 striders; ps layout unchanged.
__global__ __launch_bounds__(256) void colstats_f32_kernel(const float* __restrict__ X, int M,
                                    float* __restrict__ ps, float* __restrict__ pss,
                                    unsigned short* __restrict__ xb) {
  __shared__ float sm[8][FIN], sq[8][FIN];
  int t = threadIdx.x;
  int g = t & 31, rs = t >> 5;
  int c0 = g * 4;
  float s0 = 0.f, s1 = 0.f, s2 = 0.f, s3 = 0.f;
  float q0 = 0.f, q1 = 0.f, q2 = 0.f, q3 = 0.f;
  for (int r = blockIdx.x + 256 * rs; r < M; r += 2048) {
    float4 v = *reinterpret_cast<const float4*>(X + (size_t)r * FIN + c0);
    ushort4 p;
    p.x = f2b(v.x); p.y = f2b(v.y); p.z = f2b(v.z); p.w = f2b(v.w);
    *reinterpret_cast<ushort4*>(xb + (size_t)r * FIN + c0) = p;
    s0 += v.x; q0 += v.x * v.x;
    s1 += v.y; q1 += v.y * v.y;
    s2 += v.z; q2 += v.z * v.z;
    s3 += v.w; q3 += v.w * v.w;
  }
  sm[rs][c0 + 0] = s0; sm[rs][c0 + 1] = s1; sm[rs][c0 + 2] = s2; sm[rs][c0 + 3] = s3;
  sq[rs][c0 + 0] = q0; sq[rs][c0 + 1] = q1; sq[rs][c0 + 2] = q2; sq[rs][c0 + 3] = q3;
  __syncthreads();
  if (t < FIN) {
    float S = 0.f, Q = 0.f;
#pragma unroll
    for (int k = 0; k < 8; ++k) { S += sm[k][t]; Q += sq[k][t]; }
    ps[blockIdx.x * 256 + t] = S;
    pss[blockIdx.x * 256 + t] = Q;
  }
}

// Thread t: channel group g=t&31 (8 bf16 ch), row strider rs=t>>5 (0..7).
__global__ __launch_bounds__(256) void colstats_bf16_kernel(const unsigned short* __restrict__ X, int M,
                                     float* __restrict__ ps, float* __restrict__ pss) {
  __shared__ float sm[8][HID], sq[8][HID];
  int t = threadIdx.x;
  int g = t & 31, rs = t >> 5;
  int c0 = g * 8;
  float s0 = 0.f, s1 = 0.f, s2 = 0.f, s3 = 0.f, s4 = 0.f, s5 = 0.f, s6 = 0.f, s7 = 0.f;
  float q0 = 0.f, q1 = 0.f, q2 = 0.f, q3 = 0.f, q4 = 0.f, q5 = 0.f, q6 = 0.f, q7 = 0.f;
  for (int r = blockIdx.x + 256 * rs; r < M; r += 2048) {
    uint4 w = *reinterpret_cast<const uint4*>(X + (size_t)r * HID + c0);
    float v;
    v = b2f((unsigned short)(w.x & 0xffff)); s0 += v; q0 += v * v;
    v = b2f((unsigned short)(w.x >> 16));    s1 += v; q1 += v * v;
    v = b2f((unsigned short)(w.y & 0xffff)); s2 += v; q2 += v * v;
    v = b2f((unsigned short)(w.y >> 16));    s3 += v; q3 += v * v;
    v = b2f((unsigned short)(w.z & 0xffff)); s4 += v; q4 += v * v;
    v = b2f((unsigned short)(w.z >> 16));    s5 += v; q5 += v * v;
    v = b2f((unsigned short)(w.w & 0xffff)); s6 += v; q6 += v * v;
    v = b2f((unsigned short)(w.w >> 16));    s7 += v; q7 += v * v;
  }
  sm[rs][c0 + 0] = s0; sm[rs][c0 + 1] = s1; sm[rs][c0 + 2] = s2; sm[rs][c0 + 3] = s3;
  sm[rs][c0 + 4] = s4; sm[rs][c0 + 5] = s5; sm[rs][c0 + 6] = s6; sm[rs][c0 + 7] = s7;
  sq[rs][c0 + 0] = q0; sq[rs][c0 + 1] = q1; sq[rs][c0 + 2] = q2; sq[rs][c0 + 3] = q3;
  sq[rs][c0 + 4] = q4; sq[rs][c0 + 5] = q5; sq[rs][c0 + 6] = q6; sq[rs][c0 + 7] = q7;
  __syncthreads();
  {
    float S = 0.f, Q = 0.f;
#pragma unroll
    for (int k = 0; k < 8; ++k) { S += sm[k][t]; Q += sq[k][t]; }
    ps[blockIdx.x * 256 + t] = S;
    pss[blockIdx.x * 256 + t] = Q;
  }
}

// one block per channel; 64 threads reduce the 256 partials
__global__ void finalize_stats(const float* __restrict__ ps, const float* __restrict__ pss,
                               const float* __restrict__ g, const float* __restrict__ b,
                               float invM, float* __restrict__ scale, float* __restrict__ shift) {
  int c = blockIdx.x, t = threadIdx.x;
  float s = 0.f, ss = 0.f;
#pragma unroll
  for (int k = 0; k < 4; ++k) {
    s  += ps[(t + k * 64) * 256 + c];
    ss += pss[(t + k * 64) * 256 + c];
  }
#pragma unroll
  for (int off = 32; off; off >>= 1) {
    s += __shfl_xor(s, off);
    ss += __shfl_xor(ss, off);
  }
  if (t == 0) {
    float m = s * invM;
    float v = ss * invM - m * m;
    float sc = g[c] * rsqrtf(v + 1e-5f);
    scale[c] = sc;
    shift[c] = b[c] - m * sc;
  }
}

// ---- weight fold: Wt[n][k] = bf16(scale[k]*W[k][n]); bias2[n] = bias_in[n] + sum_k shift[k]*W[k][n]
__global__ __launch_bounds__(256) void wfold_kernel(const float* __restrict__ W,
    const float* __restrict__ scale, const float* __restrict__ shift,
    const float* __restrict__ bias_in, unsigned short* __restrict__ Wt,
    float* __restrict__ bias2, int K) {
  int n = blockIdx.x;   // 256
  int t = threadIdx.x;  // 256
  float part = 0.f;
  if (t < K) {
    float wv = W[(size_t)t * 256 + n];
    Wt[(size_t)n * K + t] = f2b(scale[t] * wv);
    part = shift[t] * wv;
  }
  __shared__ float red[256];
  red[t] = part;
  __syncthreads();
  if (t < 128) red[t] += red[t + 128];
  __syncthreads();
  if (t < 64) {
    float s = red[t] + red[t + 64];
#pragma unroll
    for (int off = 32; off; off >>= 1) s += __shfl_xor(s, off);
    if (t == 0) bias2[n] = (bias_in ? bias_in[n] : 0.f) + s;
  }
}

// ---- pure-bf16 MFMA GEMM + fused attention logits (direct store, no atomics) ----
// C = [relu]( A @ Wt^T + bias2 ); tile 128x128x32, 4 waves (2x2), N fixed 256.
// Block cols [bn,bn+128) = heads (bn>>6)+0 and +1; wave wn owns head (bn>>6)+wn,
// so als[row,head]/ald[row,head] are computed completely within one wave.
__global__ __launch_bounds__(256) void gemm_bf16_kernel(
    const unsigned short* __restrict__ Ab, const unsigned short* __restrict__ Wt,
    const float* __restrict__ bias2, unsigned short* __restrict__ Cb,
    int M, int K, int do_relu,
    float* __restrict__ als, float* __restrict__ ald,
    const float* __restrict__ asrc, const float* __restrict__ adst) {
  __shared__ unsigned short Am[128][40];  // rows padded to 80B (16B aligned)
  __shared__ unsigned short Bn[128][40];
  int tid = threadIdx.x;
  int lane = tid & 63, wid = tid >> 6;
  int wm = wid >> 1, wn = wid & 1;
  int bm = blockIdx.x * 128, bn = blockIdx.y * 128;
  int lrow = lane & 15, lkh = (lane >> 4) * 8;
  int sr = tid >> 2;   // 0..63
  int ssg = tid & 3;   // 16B segment in k (8 bf16)

  f32x4 acc[4][4] = {};

  for (int k0 = 0; k0 < K; k0 += 32) {
    {
      int ra = min(bm + sr, M - 1);
      uint4 v0 = *reinterpret_cast<const uint4*>(Ab + (size_t)ra * K + k0 + ssg * 8);
      *reinterpret_cast<uint4*>(&Am[sr][ssg * 8]) = v0;
      int rb = min(bm + sr + 64, M - 1);
      uint4 v1 = *reinterpret_cast<const uint4*>(Ab + (size_t)rb * K + k0 + ssg * 8);
      *reinterpret_cast<uint4*>(&Am[sr + 64][ssg * 8]) = v1;
      uint4 w0 = *reinterpret_cast<const uint4*>(Wt + (size_t)(bn + sr) * K + k0 + ssg * 8);
      *reinterpret_cast<uint4*>(&Bn[sr][ssg * 8]) = w0;
      uint4 w1 = *reinterpret_cast<const uint4*>(Wt + (size_t)(bn + sr + 64) * K + k0 + ssg * 8);
      *reinterpret_cast<uint4*>(&Bn[sr + 64][ssg * 8]) = w1;
    }
    __syncthreads();
    bf16x8 af[4], bfr[4];
#pragma unroll
    for (int i = 0; i < 4; ++i)
      af[i] = *reinterpret_cast<const bf16x8*>(&Am[wm * 64 + i * 16 + lrow][lkh]);
#pragma unroll
    for (int j = 0; j < 4; ++j)
      bfr[j] = *reinterpret_cast<const bf16x8*>(&Bn[wn * 64 + j * 16 + lrow][lkh]);
#pragma unroll
    for (int i = 0; i < 4; ++i)
#pragma unroll
      for (int j = 0; j < 4; ++j)
        acc[i][j] = __builtin_amdgcn_mfma_f32_16x16x32_bf16(af[i], bfr[j], acc[i][j], 0, 0, 0);
    __syncthreads();
  }

  int r4 = (lane >> 4) * 4;
  bool att = (als != nullptr);
  int head = (bn >> 6) + wn;
  float bv[4], asv[4], adv[4];
#pragma unroll
  for (int j = 0; j < 4; ++j) {
    int colv = bn + wn * 64 + j * 16 + lrow;
    bv[j] = bias2[colv];
    if (att) { asv[j] = asrc[colv]; adv[j] = adst[colv]; }
  }
#pragma unroll
  for (int i = 0; i < 4; ++i) {
#pragma unroll
    for (int r = 0; r < 4; ++r) {
      int row = bm + wm * 64 + i * 16 + r4 + r;
      float ps = 0.f, pd = 0.f;
#pragma unroll
      for (int j = 0; j < 4; ++j) {
        int colv = bn + wn * 64 + j * 16 + lrow;
        float v = acc[i][j][r] + bv[j];
        if (do_relu) v = fmaxf(v, 0.f);
        if (row < M) Cb[(size_t)row * HID + colv] = f2b(v);
        if (att) { ps += v * asv[j]; pd += v * adv[j]; }
      }
      if (att) {
#pragma unroll
        for (int off = 1; off < 16; off <<= 1) {
          ps += __shfl_xor(ps, off);
          pd += __shfl_xor(pd, off);
        }
        if (lrow == 0 && row < M) {
          als[row * 4 + head] = ps;
          ald[row * 4 + head] = pd;
        }
      }
    }
  }
}

// ---- CSR build (dst identical across layers; build once) ----
__device__ __forceinline__ void edge_sd(const int* __restrict__ ei, int e, int& s, int& d) {
  if (e < NE) { s = ei[e]; d = ei[NE + e]; }
  else        { s = e - NE; d = s; }
}

__global__ void hist_kernel(const int* __restrict__ ei, int* __restrict__ deg) {
  int e = blockIdx.x * blockDim.x + threadIdx.x;
  if (e >= NTOT) return;
  int s, d; edge_sd(ei, e, s, d);
  atomicAdd(&deg[d], 1);
}

__global__ __launch_bounds__(1024) void scan_kernel(const int* __restrict__ deg,
                                                    int* __restrict__ rp,
                                                    int* __restrict__ cursor) {
  __shared__ int part[1024];
  int t = threadIdx.x;
  const int C = (NN + 1023) / 1024;
  int base = t * C;
  int s = 0;
  for (int i = 0; i < C; ++i) {
    int idx = base + i;
    if (idx < NN) s += deg[idx];
  }
  part[t] = s;
  __syncthreads();
  for (int off = 1; off < 1024; off <<= 1) {
    int u = (t >= off) ? part[t - off] : 0;
    __syncthreads();
    part[t] += u;
    __syncthreads();
  }
  int run = part[t] - s;
  for (int i = 0; i < C; ++i) {
    int idx = base + i;
    if (idx < NN) {
      rp[idx] = run;
      cursor[idx] = run;
      run += deg[idx];
    }
  }
  if (t == 1023) rp[NN] = part[1023];
}

__global__ void scatter_kernel(const int* __restrict__ ei, int* __restrict__ cursor,
                               int* __restrict__ col) {
  int e = blockIdx.x * blockDim.x + threadIdx.x;
  if (e >= NTOT) return;
  int s, d; edge_sd(ei, e, s, d);
  int pos = atomicAdd(&cursor[d], 1);
  col[pos] = s;
}

// ---- fused GAT aggregation: ONE WAVE PER NODE, single-exp, unrolled rounds ----
__global__ __launch_bounds__(256) void gat_agg_kernel(
    const int* __restrict__ rp, const int* __restrict__ col,
    const float* __restrict__ als, const float* __restrict__ ald,
    const unsigned short* __restrict__ xp, const float* __restrict__ bias,
    unsigned short* __restrict__ out) {
  int wv = threadIdx.x >> 6, lane = threadIdx.x & 63;
  int n = blockIdx.x * 4 + wv;
  if (n >= NN) return;
  int beg = rp[n], deg = rp[n + 1] - beg;
  int hh = lane & 3;       // head this lane computes logits for
  int jof = lane >> 2;     // edge offset within a 16-edge round
  float aldh = ald[n * 4 + hh];
  int full = deg & ~15;
  int rem = deg - full;
  // phase A: global max per head
  float m = -1e30f;
  for (int r0 = 0; r0 < full; r0 += 16) {
    int s = col[beg + r0 + jof];
    float l = als[s * 4 + hh] + aldh;
    l = l > 0.f ? l : 0.2f * l;
    m = fmaxf(m, l);
  }
  if (jof < rem) {
    int s = col[beg + full + jof];
    float l = als[s * 4 + hh] + aldh;
    l = l > 0.f ? l : 0.2f * l;
    m = fmaxf(m, l);
  }
#pragma unroll
  for (int off = 4; off < 64; off <<= 1) m = fmaxf(m, __shfl_xor(m, off));
  // phase B: exp + unnormalized gather + ssum
  int c0 = lane * 4;       // this lane's 4 output channels
  int hme = lane >> 4;     // head of those channels
  float ss = 0.f;
  float a0 = 0.f, a1 = 0.f, a2 = 0.f, a3 = 0.f;
  for (int r0 = 0; r0 < full; r0 += 16) {
    int sreg = col[beg + r0 + jof];
    float l = als[sreg * 4 + hh] + aldh;
    l = l > 0.f ? l : 0.2f * l;
    float cf = __expf(l - m);
    ss += cf;
#pragma unroll
    for (int jj = 0; jj < 16; ++jj) {
      int s = __shfl(sreg, jj << 2);
      float c = __shfl(cf, (jj << 2) | hme);
      uint2 w = *reinterpret_cast<const uint2*>(xp + (size_t)s * HID + c0);
      a0 += c * b2f((unsigned short)(w.x & 0xffff));
      a1 += c * b2f((unsigned short)(w.x >> 16));
      a2 += c * b2f((unsigned short)(w.y & 0xffff));
      a3 += c * b2f((unsigned short)(w.y >> 16));
    }
  }
  if (rem) {
    int sreg = 0;
    float cf = 0.f;
    if (jof < rem) {
      sreg = col[beg + full + jof];
      float l = als[sreg * 4 + hh] + aldh;
      l = l > 0.f ? l : 0.2f * l;
      cf = __expf(l - m);
      ss += cf;
    }
    for (int jj = 0; jj < rem; ++jj) {
      int s = __shfl(sreg, jj << 2);
      float c = __shfl(cf, (jj << 2) | hme);
      uint2 w = *reinterpret_cast<const uint2*>(xp + (size_t)s * HID + c0);
      a0 += c * b2f((unsigned short)(w.x & 0xffff));
      a1 += c * b2f((unsigned short)(w.x >> 16));
      a2 += c * b2f((unsigned short)(w.y & 0xffff));
      a3 += c * b2f((unsigned short)(w.y >> 16));
    }
  }
#pragma unroll
  for (int off = 4; off < 64; off <<= 1) ss += __shfl_xor(ss, off);
  float inv = 1.0f / __shfl(ss, hme);   // lane hme holds the total for head hme
  float4 bvv = *reinterpret_cast<const float4*>(bias + c0);
  ushort4 o;
  o.x = f2b(fmaxf(a0 * inv + bvv.x, 0.f));
  o.y = f2b(fmaxf(a1 * inv + bvv.y, 0.f));
  o.z = f2b(fmaxf(a2 * inv + bvv.z, 0.f));
  o.w = f2b(fmaxf(a3 * inv + bvv.w, 0.f));
  *reinterpret_cast<ushort4*>(out + (size_t)n * HID + c0) = o;
}

// ---- pool: 256 blocks over contiguous node ranges, boundary atomics ----
__global__ void pool_kernel(const unsigned short* __restrict__ h, const int* __restrict__ batch,
                            float* __restrict__ g) {
  const int ROWS = (NN + 255) / 256;
  int r0 = blockIdx.x * ROWS;
  int r1 = min(r0 + ROWS, NN);
  if (r0 >= r1) return;
  int c = threadIdx.x;
  int cur = batch[r0];
  float acc = 0.f;
  for (int r = r0; r < r1; ++r) {
    int b = batch[r];
    if (b != cur) {
      atomicAdd(&g[(size_t)cur * HID + c], acc);
      acc = 0.f;
      cur = b;
    }
    acc += b2f(h[(size_t)r * HID + c]);
  }
  atomicAdd(&g[(size_t)cur * HID + c], acc);
}

// ---- tail: BN (redundant per-block stats, L2-hot) fused into consumers ----
__global__ void fc_bn_kernel(const float* __restrict__ gin, const float* __restrict__ gamma,
                             const float* __restrict__ beta, const float* __restrict__ W,
                             const float* __restrict__ b, float* __restrict__ gout) {
  __shared__ float row[HID];
  int g = blockIdx.x, t = threadIdx.x;  // 256
  float s = 0.f, ss = 0.f;
  for (int r = 0; r < NG; ++r) {
    float v = gin[r * HID + t];
    s += v; ss += v * v;
  }
  float mn = s / NG, var = ss / NG - mn * mn;
  float sc = gamma[t] * rsqrtf(var + 1e-5f);
  float sh = beta[t] - mn * sc;
  row[t] = gin[g * HID + t] * sc + sh;
  __syncthreads();
  float acc = b[t];
  for (int k = 0; k < HID; ++k) acc += row[k] * W[k * HID + t];
  gout[g * HID + t] = fmaxf(acc, 0.f);
}

__global__ void cls_bn_kernel(const float* __restrict__ gin, const float* __restrict__ gamma,
                              const float* __restrict__ beta, const float* __restrict__ W,
                              const float* __restrict__ b, float* __restrict__ out) {
  __shared__ float row[HID];
  __shared__ float logits[NCLS];
  int g = blockIdx.x, t = threadIdx.x;
  float s = 0.f, ss = 0.f;
  for (int r = 0; r < NG; ++r) {
    float v = gin[r * HID + t];
    s += v; ss += v * v;
  }
  float mn = s / NG, var = ss / NG - mn * mn;
  float sc = gamma[t] * rsqrtf(var + 1e-5f);
  float sh = beta[t] - mn * sc;
  row[t] = gin[g * HID + t] * sc + sh;
  __syncthreads();
  if (t < NCLS) {
    float a = b[t];
    for (int k = 0; k < HID; ++k) a += row[k] * W[k * NCLS + t];
    logits[t] = a;
  }
  __syncthreads();
  if (t == 0) {
    float mxv = -1e30f;
    for (int i = 0; i < NCLS; ++i) mxv = fmaxf(mxv, logits[i]);
    float se = 0.f;
    for (int i = 0; i < NCLS; ++i) se += expf(logits[i] - mxv);
    float lse = mxv + logf(se);
    for (int i = 0; i < NCLS; ++i) out[g * NCLS + i] = logits[i] - lse;
  }
}

extern "C" void kernel_launch(void* const* d_in, const int* in_sizes, int n_in,
                              void* d_out, int out_size, void* d_ws, size_t ws_size,
                              hipStream_t stream) {
  const float* x        = (const float*)d_in[0];
  const int*   ei       = (const int*)d_in[1];
  const int*   batch    = (const int*)d_in[2];
  const float* bn_feat_g = (const float*)d_in[3];
  const float* bn_feat_b = (const float*)d_in[4];
  const float* W_feat   = (const float*)d_in[5];
  const float* b_feat   = (const float*)d_in[6];
  const float* bns_g    = (const float*)d_in[7];
  const float* bns_b    = (const float*)d_in[8];
  const float* Wg       = (const float*)d_in[9];
  const float* att_src  = (const float*)d_in[10];
  const float* att_dst  = (const float*)d_in[11];
  const float* gat_b    = (const float*)d_in[12];
  const float* bn_fc_g  = (const float*)d_in[13];
  const float* bn_fc_b  = (const float*)d_in[14];
  const float* W_fc     = (const float*)d_in[15];
  const float* b_fc     = (const float*)d_in[16];
  const float* bn_h_g   = (const float*)d_in[17];
  const float* bn_h_b   = (const float*)d_in[18];
  const float* W_cls    = (const float*)d_in[19];
  const float* b_cls    = (const float*)d_in[20];

  char* ws = (char*)d_ws;
  size_t off = 0;
  auto alloc = [&](size_t bytes) -> void* {
    void* p = ws + off;
    off += (bytes + 255) & ~(size_t)255;
    return p;
  };
  float* psum   = (float*)alloc(256 * 256 * 4);
  float* psumsq = (float*)alloc(256 * 256 * 4);
  float* scale  = (float*)alloc(HID * 4);
  float* shift  = (float*)alloc(HID * 4);
  float* bias2  = (float*)alloc(HID * 4);
  float* als    = (float*)alloc((size_t)NN * 4 * 4);
  float* ald    = (float*)alloc((size_t)NN * 4 * 4);
  int*   deg    = (int*)alloc((size_t)NN * 4);
  int*   cursor = (int*)alloc((size_t)NN * 4);
  int*   rp     = (int*)alloc((size_t)(NN + 1) * 4);
  int*   col    = (int*)alloc((size_t)NTOT * 4);
  unsigned short* xb  = (unsigned short*)alloc((size_t)NN * FIN * 2);   // x bf16
  unsigned short* Wft = (unsigned short*)alloc((size_t)HID * FIN * 2);  // folded stage0 W
  unsigned short* Wgt = (unsigned short*)alloc((size_t)HID * HID * 2);  // folded layer W (reused)
  unsigned short* bufA = (unsigned short*)alloc((size_t)NN * HID * 2);  // h (bf16)
  unsigned short* xp   = (unsigned short*)alloc((size_t)NN * HID * 2);  // xp (bf16)
  float* g0     = (float*)alloc((size_t)NG * HID * 4);
  float* g1     = (float*)alloc((size_t)NG * HID * 4);
  (void)ws_size; (void)n_in; (void)in_sizes; (void)out_size;

  const int ETHREADS = 256;
  const int EGRID = (NTOT + ETHREADS - 1) / ETHREADS;

  // ---- CSR build (independent of activations)
  hipMemsetAsync(deg, 0, (size_t)NN * 4, stream);
  hist_kernel<<<EGRID, ETHREADS, 0, stream>>>(ei, deg);
  scan_kernel<<<1, 1024, 0, stream>>>(deg, rp, cursor);
  scatter_kernel<<<EGRID, ETHREADS, 0, stream>>>(ei, cursor, col);

  // ---- stage 0: h = bf16(relu( xb @ fold(W_feat) + bias2 ))  (x cast fused in colstats)
  colstats_f32_kernel<<<256, 256, 0, stream>>>(x, NN, psum, psumsq, xb);
  finalize_stats<<<FIN, 64, 0, stream>>>(psum, psumsq, bn_feat_g, bn_feat_b,
                                         1.0f / NN, scale, shift);
  wfold_kernel<<<HID, 256, 0, stream>>>(W_feat, scale, shift, b_feat, Wft, bias2, FIN);
  gemm_bf16_kernel<<<dim3((NN + 127) / 128, 2), 256, 0, stream>>>(
      xb, Wft, bias2, bufA, NN, FIN, 1, nullptr, nullptr, nullptr, nullptr);

  // ---- 3 GAT layers
  for (int i = 0; i < 3; ++i) {
    colstats_bf16_kernel<<<256, 256, 0, stream>>>(bufA, NN, psum, psumsq);
    finalize_stats<<<HID, 64, 0, stream>>>(psum, psumsq, bns_g + i * HID, bns_b + i * HID,
                                           1.0f / NN, scale, shift);
    wfold_kernel<<<HID, 256, 0, stream>>>(Wg + (size_t)i * HID * HID, scale, shift,
                                          nullptr, Wgt, bias2, HID);
    // xp = bf16(BN(h)@Wg[i]) with fused, direct-store attention logits
    gemm_bf16_kernel<<<dim3((NN + 127) / 128, 2), 256, 0, stream>>>(
        bufA, Wgt, bias2, xp, NN, HID, 0, als, ald,
        att_src + i * HID, att_dst + i * HID);
    gat_agg_kernel<<<(NN + 3) / 4, 256, 0, stream>>>(rp, col, als, ald, xp,
                                                     gat_b + i * HID, bufA);
  }

  // ---- pool + fused tail
  hipMemsetAsync(g0, 0, (size_t)NG * HID * 4, stream);
  pool_kernel<<<256, HID, 0, stream>>>(bufA, batch, g0);
  fc_bn_kernel<<<NG, HID, 0, stream>>>(g0, bn_fc_g, bn_fc_b, W_fc, b_fc, g1);
  cls_bn_kernel<<<NG, HID, 0, stream>>>(g1, bn_h_g, bn_h_b, W_cls, b_cls, (float*)d_out);
}

// Round 14
// 322.032 us; speedup vs baseline: 1.3511x; 1.0674x over previous
//
#include <hip/hip_runtime.h>

// Problem constants (fixed by reference)
constexpr int NN   = 20000;          // nodes
constexpr int NE   = 320000;         // edges (before self-loops)
constexpr int NTOT = NE + NN;        // edges incl self-loops
constexpr int FIN  = 128;
constexpr int HID  = 256;
constexpr int NG   = 128;            // graphs
constexpr int NCLS = 10;

typedef __bf16 bf16x8 __attribute__((ext_vector_type(8)));
typedef float  f32x4  __attribute__((ext_vector_type(4)));

__device__ __forceinline__ unsigned short f2b(float f) {
  unsigned u = __float_as_uint(f);
  unsigned r = (u + 0x7fffu + ((u >> 16) & 1u)) >> 16;
  return (unsigned short)r;
}
__device__ __forceinline__ float b2f(unsigned short h) {
  return __uint_as_float((unsigned)h << 16);
}

// ---- per-column mean/var partials, VECTORIZED (grid MUST be 256 blocks, block 256) ----
__global__ __launch_bounds__(256) void colstats_f32_kernel(const float* __restrict__ X, int M,
                                    float* __restrict__ ps, float* __restrict__ pss,
                                    unsigned short* __restrict__ xb) {
  __shared__ float sm[8][FIN], sq[8][FIN];
  int t = threadIdx.x;
  int g = t & 31, rs = t >> 5;
  int c0 = g * 4;
  float s0 = 0.f, s1 = 0.f, s2 = 0.f, s3 = 0.f;
  float q0 = 0.f, q1 = 0.f, q2 = 0.f, q3 = 0.f;
  for (int r = blockIdx.x + 256 * rs; r < M; r += 2048) {
    float4 v = *reinterpret_cast<const float4*>(X + (size_t)r * FIN + c0);
    ushort4 p;
    p.x = f2b(v.x); p.y = f2b(v.y); p.z = f2b(v.z); p.w = f2b(v.w);
    *reinterpret_cast<ushort4*>(xb + (size_t)r * FIN + c0) = p;
    s0 += v.x; q0 += v.x * v.x;
    s1 += v.y; q1 += v.y * v.y;
    s2 += v.z; q2 += v.z * v.z;
    s3 += v.w; q3 += v.w * v.w;
  }
  sm[rs][c0 + 0] = s0; sm[rs][c0 + 1] = s1; sm[rs][c0 + 2] = s2; sm[rs][c0 + 3] = s3;
  sq[rs][c0 + 0] = q0; sq[rs][c0 + 1] = q1; sq[rs][c0 + 2] = q2; sq[rs][c0 + 3] = q3;
  __syncthreads();
  if (t < FIN) {
    float S = 0.f, Q = 0.f;
#pragma unroll
    for (int k = 0; k < 8; ++k) { S += sm[k][t]; Q += sq[k][t]; }
    ps[blockIdx.x * 256 + t] = S;
    pss[blockIdx.x * 256 + t] = Q;
  }
}

__global__ __launch_bounds__(256) void colstats_bf16_kernel(const unsigned short* __restrict__ X, int M,
                                     float* __restrict__ ps, float* __restrict__ pss) {
  __shared__ float sm[8][HID], sq[8][HID];
  int t = threadIdx.x;
  int g = t & 31, rs = t >> 5;
  int c0 = g * 8;
  float s0 = 0.f, s1 = 0.f, s2 = 0.f, s3 = 0.f, s4 = 0.f, s5 = 0.f, s6 = 0.f, s7 = 0.f;
  float q0 = 0.f, q1 = 0.f, q2 = 0.f, q3 = 0.f, q4 = 0.f, q5 = 0.f, q6 = 0.f, q7 = 0.f;
  for (int r = blockIdx.x + 256 * rs; r < M; r += 2048) {
    uint4 w = *reinterpret_cast<const uint4*>(X + (size_t)r * HID + c0);
    float v;
    v = b2f((unsigned short)(w.x & 0xffff)); s0 += v; q0 += v * v;
    v = b2f((unsigned short)(w.x >> 16));    s1 += v; q1 += v * v;
    v = b2f((unsigned short)(w.y & 0xffff)); s2 += v; q2 += v * v;
    v = b2f((unsigned short)(w.y >> 16));    s3 += v; q3 += v * v;
    v = b2f((unsigned short)(w.z & 0xffff)); s4 += v; q4 += v * v;
    v = b2f((unsigned short)(w.z >> 16));    s5 += v; q5 += v * v;
    v = b2f((unsigned short)(w.w & 0xffff)); s6 += v; q6 += v * v;
    v = b2f((unsigned short)(w.w >> 16));    s7 += v; q7 += v * v;
  }
  sm[rs][c0 + 0] = s0; sm[rs][c0 + 1] = s1; sm[rs][c0 + 2] = s2; sm[rs][c0 + 3] = s3;
  sm[rs][c0 + 4] = s4; sm[rs][c0 + 5] = s5; sm[rs][c0 + 6] = s6; sm[rs][c0 + 7] = s7;
  sq[rs][c0 + 0] = q0; sq[rs][c0 + 1] = q1; sq[rs][c0 + 2] = q2; sq[rs][c0 + 3] = q3;
  sq[rs][c0 + 4] = q4; sq[rs][c0 + 5] = q5; sq[rs][c0 + 6] = q6; sq[rs][c0 + 7] = q7;
  __syncthreads();
  {
    float S = 0.f, Q = 0.f;
#pragma unroll
    for (int k = 0; k < 8; ++k) { S += sm[k][t]; Q += sq[k][t]; }
    ps[blockIdx.x * 256 + t] = S;
    pss[blockIdx.x * 256 + t] = Q;
  }
}

// one block per channel; 64 threads reduce the 256 partials
__global__ void finalize_stats(const float* __restrict__ ps, const float* __restrict__ pss,
                               const float* __restrict__ g, const float* __restrict__ b,
                               float invM, float* __restrict__ scale, float* __restrict__ shift) {
  int c = blockIdx.x, t = threadIdx.x;
  float s = 0.f, ss = 0.f;
#pragma unroll
  for (int k = 0; k < 4; ++k) {
    s  += ps[(t + k * 64) * 256 + c];
    ss += pss[(t + k * 64) * 256 + c];
  }
#pragma unroll
  for (int off = 32; off; off >>= 1) {
    s += __shfl_xor(s, off);
    ss += __shfl_xor(ss, off);
  }
  if (t == 0) {
    float m = s * invM;
    float v = ss * invM - m * m;
    float sc = g[c] * rsqrtf(v + 1e-5f);
    scale[c] = sc;
    shift[c] = b[c] - m * sc;
  }
}

// ---- weight fold: Wt[n][k] = bf16(scale[k]*W[k][n]); bias2[n] = bias_in[n] + sum_k shift[k]*W[k][n]
__global__ __launch_bounds__(256) void wfold_kernel(const float* __restrict__ W,
    const float* __restrict__ scale, const float* __restrict__ shift,
    const float* __restrict__ bias_in, unsigned short* __restrict__ Wt,
    float* __restrict__ bias2, int K) {
  int n = blockIdx.x;   // 256
  int t = threadIdx.x;  // 256
  float part = 0.f;
  if (t < K) {
    float wv = W[(size_t)t * 256 + n];
    Wt[(size_t)n * K + t] = f2b(scale[t] * wv);
    part = shift[t] * wv;
  }
  __shared__ float red[256];
  red[t] = part;
  __syncthreads();
  if (t < 128) red[t] += red[t + 128];
  __syncthreads();
  if (t < 64) {
    float s = red[t] + red[t + 64];
#pragma unroll
    for (int off = 32; off; off >>= 1) s += __shfl_xor(s, off);
    if (t == 0) bias2[n] = (bias_in ? bias_in[n] : 0.f) + s;
  }
}

// ---- pure-bf16 MFMA GEMM + fused attention logits (direct store, no atomics) ----
__global__ __launch_bounds__(256) void gemm_bf16_kernel(
    const unsigned short* __restrict__ Ab, const unsigned short* __restrict__ Wt,
    const float* __restrict__ bias2, unsigned short* __restrict__ Cb,
    int M, int K, int do_relu,
    float* __restrict__ als, float* __restrict__ ald,
    const float* __restrict__ asrc, const float* __restrict__ adst) {
  __shared__ unsigned short Am[128][40];  // rows padded to 80B (16B aligned)
  __shared__ unsigned short Bn[128][40];
  int tid = threadIdx.x;
  int lane = tid & 63, wid = tid >> 6;
  int wm = wid >> 1, wn = wid & 1;
  int bm = blockIdx.x * 128, bn = blockIdx.y * 128;
  int lrow = lane & 15, lkh = (lane >> 4) * 8;
  int sr = tid >> 2;   // 0..63
  int ssg = tid & 3;   // 16B segment in k (8 bf16)

  f32x4 acc[4][4] = {};

  for (int k0 = 0; k0 < K; k0 += 32) {
    {
      int ra = min(bm + sr, M - 1);
      uint4 v0 = *reinterpret_cast<const uint4*>(Ab + (size_t)ra * K + k0 + ssg * 8);
      *reinterpret_cast<uint4*>(&Am[sr][ssg * 8]) = v0;
      int rb = min(bm + sr + 64, M - 1);
      uint4 v1 = *reinterpret_cast<const uint4*>(Ab + (size_t)rb * K + k0 + ssg * 8);
      *reinterpret_cast<uint4*>(&Am[sr + 64][ssg * 8]) = v1;
      uint4 w0 = *reinterpret_cast<const uint4*>(Wt + (size_t)(bn + sr) * K + k0 + ssg * 8);
      *reinterpret_cast<uint4*>(&Bn[sr][ssg * 8]) = w0;
      uint4 w1 = *reinterpret_cast<const uint4*>(Wt + (size_t)(bn + sr + 64) * K + k0 + ssg * 8);
      *reinterpret_cast<uint4*>(&Bn[sr + 64][ssg * 8]) = w1;
    }
    __syncthreads();
    bf16x8 af[4], bfr[4];
#pragma unroll
    for (int i = 0; i < 4; ++i)
      af[i] = *reinterpret_cast<const bf16x8*>(&Am[wm * 64 + i * 16 + lrow][lkh]);
#pragma unroll
    for (int j = 0; j < 4; ++j)
      bfr[j] = *reinterpret_cast<const bf16x8*>(&Bn[wn * 64 + j * 16 + lrow][lkh]);
#pragma unroll
    for (int i = 0; i < 4; ++i)
#pragma unroll
      for (int j = 0; j < 4; ++j)
        acc[i][j] = __builtin_amdgcn_mfma_f32_16x16x32_bf16(af[i], bfr[j], acc[i][j], 0, 0, 0);
    __syncthreads();
  }

  int r4 = (lane >> 4) * 4;
  bool att = (als != nullptr);
  int head = (bn >> 6) + wn;
  float bv[4], asv[4], adv[4];
#pragma unroll
  for (int j = 0; j < 4; ++j) {
    int colv = bn + wn * 64 + j * 16 + lrow;
    bv[j] = bias2[colv];
    if (att) { asv[j] = asrc[colv]; adv[j] = adst[colv]; }
  }
#pragma unroll
  for (int i = 0; i < 4; ++i) {
#pragma unroll
    for (int r = 0; r < 4; ++r) {
      int row = bm + wm * 64 + i * 16 + r4 + r;
      float ps = 0.f, pd = 0.f;
#pragma unroll
      for (int j = 0; j < 4; ++j) {
        int colv = bn + wn * 64 + j * 16 + lrow;
        float v = acc[i][j][r] + bv[j];
        if (do_relu) v = fmaxf(v, 0.f);
        if (row < M) Cb[(size_t)row * HID + colv] = f2b(v);
        if (att) { ps += v * asv[j]; pd += v * adv[j]; }
      }
      if (att) {
#pragma unroll
        for (int off = 1; off < 16; off <<= 1) {
          ps += __shfl_xor(ps, off);
          pd += __shfl_xor(pd, off);
        }
        if (lrow == 0 && row < M) {
          als[row * 4 + head] = ps;
          ald[row * 4 + head] = pd;
        }
      }
    }
  }
}

// ---- CSR build (dst identical across layers; build once) ----
__device__ __forceinline__ void edge_sd(const int* __restrict__ ei, int e, int& s, int& d) {
  if (e < NE) { s = ei[e]; d = ei[NE + e]; }
  else        { s = e - NE; d = s; }
}

__global__ void hist_kernel(const int* __restrict__ ei, int* __restrict__ deg) {
  int e = blockIdx.x * blockDim.x + threadIdx.x;
  if (e >= NTOT) return;
  int s, d; edge_sd(ei, e, s, d);
  atomicAdd(&deg[d], 1);
}

__global__ __launch_bounds__(1024) void scan_kernel(const int* __restrict__ deg,
                                                    int* __restrict__ rp,
                                                    int* __restrict__ cursor) {
  __shared__ int part[1024];
  int t = threadIdx.x;
  const int C = (NN + 1023) / 1024;
  int base = t * C;
  int s = 0;
  for (int i = 0; i < C; ++i) {
    int idx = base + i;
    if (idx < NN) s += deg[idx];
  }
  part[t] = s;
  __syncthreads();
  for (int off = 1; off < 1024; off <<= 1) {
    int u = (t >= off) ? part[t - off] : 0;
    __syncthreads();
    part[t] += u;
    __syncthreads();
  }
  int run = part[t] - s;
  for (int i = 0; i < C; ++i) {
    int idx = base + i;
    if (idx < NN) {
      rp[idx] = run;
      cursor[idx] = run;
      run += deg[idx];
    }
  }
  if (t == 1023) rp[NN] = part[1023];
}

__global__ void scatter_kernel(const int* __restrict__ ei, int* __restrict__ cursor,
                               int* __restrict__ col) {
  int e = blockIdx.x * blockDim.x + threadIdx.x;
  if (e >= NTOT) return;
  int s, d; edge_sd(ei, e, s, d);
  int pos = atomicAdd(&cursor[d], 1);
  col[pos] = s;
}

// ---- fused GAT aggregation: ONE WAVE PER NODE; (col,logit) register-cached ----
// Phase A computes per-edge logits once, caching up to 4 rounds (deg<=64) in
// statically-indexed registers; phase B reuses them (no col/als re-reads).
// Overflow rounds (deg>64, ~never for Poisson(16)+1) fall back to recompute.
__global__ __launch_bounds__(256) void gat_agg_kernel(
    const int* __restrict__ rp, const int* __restrict__ col,
    const float* __restrict__ als, const float* __restrict__ ald,
    const unsigned short* __restrict__ xp, const float* __restrict__ bias,
    unsigned short* __restrict__ out) {
  int wv = threadIdx.x >> 6, lane = threadIdx.x & 63;
  int n = blockIdx.x * 4 + wv;
  if (n >= NN) return;
  int beg = rp[n], deg = rp[n + 1] - beg;   // deg >= 1 (self-loop)
  int hh = lane & 3;       // head this lane computes logits for
  int jof = lane >> 2;     // edge offset within a 16-edge round
  float aldh = ald[n * 4 + hh];
  const int MAXR = 4;
  int   sN[MAXR];
  float lN[MAXR];
  int nr = (deg + 15) >> 4;
  int nrc = nr < MAXR ? nr : MAXR;
  // phase A: per-lane logits (cached) + running max
  float m = -1e30f;
#pragma unroll
  for (int r = 0; r < MAXR; ++r) {
    int s = 0; float l = -1e30f;
    if (r < nrc) {
      int j = r * 16 + jof;
      if (j < deg) {
        s = col[beg + j];
        l = als[s * 4 + hh] + aldh;
        l = l > 0.f ? l : 0.2f * l;
        m = fmaxf(m, l);
      }
    }
    sN[r] = s; lN[r] = l;
  }
  for (int r = MAXR; r < nr; ++r) {   // overflow: max only
    int j = r * 16 + jof;
    if (j < deg) {
      int s = col[beg + j];
      float l = als[s * 4 + hh] + aldh;
      l = l > 0.f ? l : 0.2f * l;
      m = fmaxf(m, l);
    }
  }
#pragma unroll
  for (int off = 4; off < 64; off <<= 1) m = fmaxf(m, __shfl_xor(m, off));
  // phase B: exp of cached logits + gather + ssum (no memory on the coef path)
  int c0 = lane * 4;       // this lane's 4 output channels
  int hme = lane >> 4;     // head of those channels
  float ss = 0.f;
  float a0 = 0.f, a1 = 0.f, a2 = 0.f, a3 = 0.f;
#pragma unroll
  for (int r = 0; r < MAXR; ++r) {
    if (r < nrc) {
      int sreg = sN[r];
      float cf = __expf(lN[r] - m);   // invalid slots: exp(-1e30-m) == 0
      ss += cf;
      int cnt = min(16, deg - r * 16);
      if (cnt == 16) {
#pragma unroll
        for (int jj = 0; jj < 16; ++jj) {
          int s = __shfl(sreg, jj << 2);
          float c = __shfl(cf, (jj << 2) | hme);
          uint2 w = *reinterpret_cast<const uint2*>(xp + (size_t)s * HID + c0);
          a0 += c * b2f((unsigned short)(w.x & 0xffff));
          a1 += c * b2f((unsigned short)(w.x >> 16));
          a2 += c * b2f((unsigned short)(w.y & 0xffff));
          a3 += c * b2f((unsigned short)(w.y >> 16));
        }
      } else {
        for (int jj = 0; jj < cnt; ++jj) {
          int s = __shfl(sreg, jj << 2);
          float c = __shfl(cf, (jj << 2) | hme);
          uint2 w = *reinterpret_cast<const uint2*>(xp + (size_t)s * HID + c0);
          a0 += c * b2f((unsigned short)(w.x & 0xffff));
          a1 += c * b2f((unsigned short)(w.x >> 16));
          a2 += c * b2f((unsigned short)(w.y & 0xffff));
          a3 += c * b2f((unsigned short)(w.y >> 16));
        }
      }
    }
  }
  for (int r = MAXR; r < nr; ++r) {   // overflow: recompute path
    int j = r * 16 + jof;
    int sreg = 0;
    float cf = 0.f;
    if (j < deg) {
      sreg = col[beg + j];
      float l = als[sreg * 4 + hh] + aldh;
      l = l > 0.f ? l : 0.2f * l;
      cf = __expf(l - m);
      ss += cf;
    }
    int cnt = min(16, deg - r * 16);
    for (int jj = 0; jj < cnt; ++jj) {
      int s = __shfl(sreg, jj << 2);
      float c = __shfl(cf, (jj << 2) | hme);
      uint2 w = *reinterpret_cast<const uint2*>(xp + (size_t)s * HID + c0);
      a0 += c * b2f((unsigned short)(w.x & 0xffff));
      a1 += c * b2f((unsigned short)(w.x >> 16));
      a2 += c * b2f((unsigned short)(w.y & 0xffff));
      a3 += c * b2f((unsigned short)(w.y >> 16));
    }
  }
#pragma unroll
  for (int off = 4; off < 64; off <<= 1) ss += __shfl_xor(ss, off);
  float inv = 1.0f / __shfl(ss, hme);   // lane hme holds the total for head hme
  float4 bvv = *reinterpret_cast<const float4*>(bias + c0);
  ushort4 o;
  o.x = f2b(fmaxf(a0 * inv + bvv.x, 0.f));
  o.y = f2b(fmaxf(a1 * inv + bvv.y, 0.f));
  o.z = f2b(fmaxf(a2 * inv + bvv.z, 0.f));
  o.w = f2b(fmaxf(a3 * inv + bvv.w, 0.f));
  *reinterpret_cast<ushort4*>(out + (size_t)n * HID + c0) = o;
}

// ---- pool: 256 blocks over contiguous node ranges, vectorized (uint2 loads) ----
// 256 threads = 64 channel-groups x 4 row-striders; per-strider boundary flush
// (valid: batch sorted => each strider's subsequence is monotone).
__global__ void pool_kernel(const unsigned short* __restrict__ h, const int* __restrict__ batch,
                            float* __restrict__ g) {
  const int ROWS = (NN + 255) / 256;
  int r0 = blockIdx.x * ROWS;
  int r1 = min(r0 + ROWS, NN);
  if (r0 >= r1) return;
  int t = threadIdx.x;
  int cg = t & 63, rs = t >> 6;
  int c0 = cg * 4;
  float a0 = 0.f, a1 = 0.f, a2 = 0.f, a3 = 0.f;
  int cur = -1;
  for (int r = r0 + rs; r < r1; r += 4) {
    int b = batch[r];
    if (b != cur) {
      if (cur >= 0) {
        atomicAdd(&g[(size_t)cur * HID + c0 + 0], a0);
        atomicAdd(&g[(size_t)cur * HID + c0 + 1], a1);
        atomicAdd(&g[(size_t)cur * HID + c0 + 2], a2);
        atomicAdd(&g[(size_t)cur * HID + c0 + 3], a3);
        a0 = a1 = a2 = a3 = 0.f;
      }
      cur = b;
    }
    uint2 w = *reinterpret_cast<const uint2*>(h + (size_t)r * HID + c0);
    a0 += b2f((unsigned short)(w.x & 0xffff));
    a1 += b2f((unsigned short)(w.x >> 16));
    a2 += b2f((unsigned short)(w.y & 0xffff));
    a3 += b2f((unsigned short)(w.y >> 16));
  }
  if (cur >= 0) {
    atomicAdd(&g[(size_t)cur * HID + c0 + 0], a0);
    atomicAdd(&g[(size_t)cur * HID + c0 + 1], a1);
    atomicAdd(&g[(size_t)cur * HID + c0 + 2], a2);
    atomicAdd(&g[(size_t)cur * HID + c0 + 3], a3);
  }
}

// ---- tail: BN (redundant per-block stats, L2-hot) fused into consumers ----
__global__ void fc_bn_kernel(const float* __restrict__ gin, const float* __restrict__ gamma,
                             const float* __restrict__ beta, const float* __restrict__ W,
                             const float* __restrict__ b, float* __restrict__ gout) {
  __shared__ float row[HID];
  int g = blockIdx.x, t = threadIdx.x;  // 256
  float s = 0.f, ss = 0.f;
  for (int r = 0; r < NG; ++r) {
    float v = gin[r * HID + t];
    s += v; ss += v * v;
  }
  float mn = s / NG, var = ss / NG - mn * mn;
  float sc = gamma[t] * rsqrtf(var + 1e-5f);
  float sh = beta[t] - mn * sc;
  row[t] = gin[g * HID + t] * sc + sh;
  __syncthreads();
  float acc = b[t];
  for (int k = 0; k < HID; ++k) acc += row[k] * W[k * HID + t];
  gout[g * HID + t] = fmaxf(acc, 0.f);
}

__global__ void cls_bn_kernel(const float* __restrict__ gin, const float* __restrict__ gamma,
                              const float* __restrict__ beta, const float* __restrict__ W,
                              const float* __restrict__ b, float* __restrict__ out) {
  __shared__ float row[HID];
  __shared__ float logits[NCLS];
  int g = blockIdx.x, t = threadIdx.x;
  float s = 0.f, ss = 0.f;
  for (int r = 0; r < NG; ++r) {
    float v = gin[r * HID + t];
    s += v; ss += v * v;
  }
  float mn = s / NG, var = ss / NG - mn * mn;
  float sc = gamma[t] * rsqrtf(var + 1e-5f);
  float sh = beta[t] - mn * sc;
  row[t] = gin[g * HID + t] * sc + sh;
  __syncthreads();
  if (t < NCLS) {
    float a = b[t];
    for (int k = 0; k < HID; ++k) a += row[k] * W[k * NCLS + t];
    logits[t] = a;
  }
  __syncthreads();
  if (t == 0) {
    float mxv = -1e30f;
    for (int i = 0; i < NCLS; ++i) mxv = fmaxf(mxv, logits[i]);
    float se = 0.f;
    for (int i = 0; i < NCLS; ++i) se += expf(logits[i] - mxv);
    float lse = mxv + logf(se);
    for (int i = 0; i < NCLS; ++i) out[g * NCLS + i] = logits[i] - lse;
  }
}

extern "C" void kernel_launch(void* const* d_in, const int* in_sizes, int n_in,
                              void* d_out, int out_size, void* d_ws, size_t ws_size,
                              hipStream_t stream) {
  const float* x        = (const float*)d_in[0];
  const int*   ei       = (const int*)d_in[1];
  const int*   batch    = (const int*)d_in[2];
  const float* bn_feat_g = (const float*)d_in[3];
  const float* bn_feat_b = (const float*)d_in[4];
  const float* W_feat   = (const float*)d_in[5];
  const float* b_feat   = (const float*)d_in[6];
  const float* bns_g    = (const float*)d_in[7];
  const float* bns_b    = (const float*)d_in[8];
  const float* Wg       = (const float*)d_in[9];
  const float* att_src  = (const float*)d_in[10];
  const float* att_dst  = (const float*)d_in[11];
  const float* gat_b    = (const float*)d_in[12];
  const float* bn_fc_g  = (const float*)d_in[13];
  const float* bn_fc_b  = (const float*)d_in[14];
  const float* W_fc     = (const float*)d_in[15];
  const float* b_fc     = (const float*)d_in[16];
  const float* bn_h_g   = (const float*)d_in[17];
  const float* bn_h_b   = (const float*)d_in[18];
  const float* W_cls    = (const float*)d_in[19];
  const float* b_cls    = (const float*)d_in[20];

  char* ws = (char*)d_ws;
  size_t off = 0;
  auto alloc = [&](size_t bytes) -> void* {
    void* p = ws + off;
    off += (bytes + 255) & ~(size_t)255;
    return p;
  };
  float* psum   = (float*)alloc(256 * 256 * 4);
  float* psumsq = (float*)alloc(256 * 256 * 4);
  float* scale  = (float*)alloc(HID * 4);
  float* shift  = (float*)alloc(HID * 4);
  float* bias2  = (float*)alloc(HID * 4);
  float* als    = (float*)alloc((size_t)NN * 4 * 4);
  float* ald    = (float*)alloc((size_t)NN * 4 * 4);
  int*   deg    = (int*)alloc((size_t)NN * 4);
  int*   cursor = (int*)alloc((size_t)NN * 4);
  int*   rp     = (int*)alloc((size_t)(NN + 1) * 4);
  int*   col    = (int*)alloc((size_t)NTOT * 4);
  unsigned short* xb  = (unsigned short*)alloc((size_t)NN * FIN * 2);   // x bf16
  unsigned short* Wft = (unsigned short*)alloc((size_t)HID * FIN * 2);  // folded stage0 W
  unsigned short* Wgt = (unsigned short*)alloc((size_t)HID * HID * 2);  // folded layer W (reused)
  unsigned short* bufA = (unsigned short*)alloc((size_t)NN * HID * 2);  // h (bf16)
  unsigned short* xp   = (unsigned short*)alloc((size_t)NN * HID * 2);  // xp (bf16)
  float* g0     = (float*)alloc((size_t)NG * HID * 4);
  float* g1     = (float*)alloc((size_t)NG * HID * 4);
  (void)ws_size; (void)n_in; (void)in_sizes; (void)out_size;

  const int ETHREADS = 256;
  const int EGRID = (NTOT + ETHREADS - 1) / ETHREADS;

  // ---- CSR build (independent of activations)
  hipMemsetAsync(deg, 0, (size_t)NN * 4, stream);
  hist_kernel<<<EGRID, ETHREADS, 0, stream>>>(ei, deg);
  scan_kernel<<<1, 1024, 0, stream>>>(deg, rp, cursor);
  scatter_kernel<<<EGRID, ETHREADS, 0, stream>>>(ei, cursor, col);

  // ---- stage 0: h = bf16(relu( xb @ fold(W_feat) + bias2 ))  (x cast fused in colstats)
  colstats_f32_kernel<<<256, 256, 0, stream>>>(x, NN, psum, psumsq, xb);
  finalize_stats<<<FIN, 64, 0, stream>>>(psum, psumsq, bn_feat_g, bn_feat_b,
                                         1.0f / NN, scale, shift);
  wfold_kernel<<<HID, 256, 0, stream>>>(W_feat, scale, shift, b_feat, Wft, bias2, FIN);
  gemm_bf16_kernel<<<dim3((NN + 127) / 128, 2), 256, 0, stream>>>(
      xb, Wft, bias2, bufA, NN, FIN, 1, nullptr, nullptr, nullptr, nullptr);

  // ---- 3 GAT layers
  for (int i = 0; i < 3; ++i) {
    colstats_bf16_kernel<<<256, 256, 0, stream>>>(bufA, NN, psum, psumsq);
    finalize_stats<<<HID, 64, 0, stream>>>(psum, psumsq, bns_g + i * HID, bns_b + i * HID,
                                           1.0f / NN, scale, shift);
    wfold_kernel<<<HID, 256, 0, stream>>>(Wg + (size_t)i * HID * HID, scale, shift,
                                          nullptr, Wgt, bias2, HID);
    // xp = bf16(BN(h)@Wg[i]) with fused, direct-store attention logits
    gemm_bf16_kernel<<<dim3((NN + 127) / 128, 2), 256, 0, stream>>>(
        bufA, Wgt, bias2, xp, NN, HID, 0, als, ald,
        att_src + i * HID, att_dst + i * HID);
    gat_agg_kernel<<<(NN + 3) / 4, 256, 0, stream>>>(rp, col, als, ald, xp,
                                                     gat_b + i * HID, bufA);
  }

  // ---- pool + fused tail
  hipMemsetAsync(g0, 0, (size_t)NG * HID * 4, stream);
  pool_kernel<<<256, HID, 0, stream>>>(bufA, batch, g0);
  fc_bn_kernel<<<NG, HID, 0, stream>>>(g0, bn_fc_g, bn_fc_b, W_fc, b_fc, g1);
  cls_bn_kernel<<<NG, HID, 0, stream>>>(g1, bn_h_g, bn_h_b, W_cls, b_cls, (float*)d_out);
}